// Round 15
// baseline (203.912 us; speedup 1.0000x reference)
//
#include <hip/hip_runtime.h>
#include <hip/hip_bf16.h>

#define BB 16
#define NN 1024
#define DD 5
#define RH 8

typedef unsigned long long u64;
typedef unsigned int u32;
typedef __hip_bfloat16 bf16;

static __device__ __forceinline__ float tof(bf16 x) { return __bfloat162float(x); }
// runtime-dtype load: f32 storage if f==true else bf16
static __device__ __forceinline__ float ldf(const void* p, long long i, bool f) {
  return f ? ((const float*)p)[i] : tof(((const bf16*)p)[i]);
}
// agent-scope (cross-XCD coherent) single-element access — per-access cache
// bypass bits, NOT a cache flush (r9 lesson: device fences are ~14us/1000).
static __device__ __forceinline__ void stG(float* p, float v) {
  __hip_atomic_store(p, v, __ATOMIC_RELAXED, __HIP_MEMORY_SCOPE_AGENT);
}
static __device__ __forceinline__ float ldG(const float* p) {
  return __hip_atomic_load(p, __ATOMIC_RELAXED, __HIP_MEMORY_SCOPE_AGENT);
}

#define LOG2E 1.4426950408889634f
#define PACK_BLOCKS (BB * NN * 16 / 256)  // 1024
#define KV_BLOCKS (BB * NN / 256)         // 64

// ---------------------------------------------------------------- pack + kv
// Identical to the proven r12 kernel, plus block 0 zero-inits the tail
// bookkeeping (pairCnt/doneCnt/pooled) used by k_attn's fused finalize.
__global__ __launch_bounds__(256) void k_pack(
    const void* __restrict__ adj, const void* __restrict__ feats,
    const void* __restrict__ coors,
    const void* __restrict__ Wk, const void* __restrict__ Wv,
    const void* __restrict__ Wo,
    u64* __restrict__ adjbits, float4* __restrict__ kvg,
    float* __restrict__ czg, int* __restrict__ gflags,
    int* __restrict__ pairCnt, int* __restrict__ doneCnt,
    float* __restrict__ pooled) {
  __shared__ int sNon01, sNonpair, sLow3;
  __shared__ int sCnt[4];
  __shared__ float wkL[25], wvL[25], woL[25];
  int tid = threadIdx.x;

  if (blockIdx.x >= PACK_BLOCKS) {
    // ---------------- kv precompute role ----------------
    int kb = blockIdx.x - PACK_BLOCKS;
    {
      u32 x = ((const u32*)feats)[tid];
      u32 lo = x & 0xFFFFu;
      int e = (int)((lo >> 7) & 0xFFu);
      bool insane = !(lo == 0u || (e >= 90 && e <= 150));
      u64 m = __ballot(insane);
      if ((tid & 63) == 0) sCnt[tid >> 6] = (int)__popcll(m);
    }
    __syncthreads();
    bool f32 = (sCnt[0] + sCnt[1] + sCnt[2] + sCnt[3]) > 64;
    if (tid < 25) {
      wkL[tid] = ldf(Wk, tid, f32);
      wvL[tid] = ldf(Wv, tid, f32);
      woL[tid] = ldf(Wo, tid, f32);
    }
    if (kb == 0 && tid == 0) gflags[0] = f32 ? 1 : 0;
    __syncthreads();
    long long node = (long long)kb * 256 + tid;  // < BB*NN
    float f0 = ldf(feats, node * DD + 0, f32), f1 = ldf(feats, node * DD + 1, f32),
          f2 = ldf(feats, node * DD + 2, f32), f3 = ldf(feats, node * DD + 3, f32),
          f4 = ldf(feats, node * DD + 4, f32);
    float k[DD], tv[DD], v[DD];
    #pragma unroll
    for (int e = 0; e < DD; ++e) {
      k[e] = f0 * wkL[e] + f1 * wkL[5 + e] + f2 * wkL[10 + e] + f3 * wkL[15 + e] +
             f4 * wkL[20 + e];
      tv[e] = f0 * wvL[e] + f1 * wvL[5 + e] + f2 * wvL[10 + e] + f3 * wvL[15 + e] +
              f4 * wvL[20 + e];
    }
    #pragma unroll
    for (int e = 0; e < DD; ++e)
      v[e] = tv[0] * woL[e] + tv[1] * woL[5 + e] + tv[2] * woL[10 + e] +
             tv[3] * woL[15 + e] + tv[4] * woL[20 + e];
    float cx = ldf(coors, node * 3 + 0, f32);
    float cy = ldf(coors, node * 3 + 1, f32);
    float cz = ldf(coors, node * 3 + 2, f32);
    kvg[node * 3 + 0] = make_float4(k[0], k[1], k[2], k[3]);
    kvg[node * 3 + 1] = make_float4(k[4], v[0], v[1], v[2]);
    kvg[node * 3 + 2] = make_float4(v[3], v[4], cx, cy);
    czg[node] = cz;
    return;
  }

  // ---------------- adjacency pack role ----------------
  if (blockIdx.x == 0) {
    for (int i = tid; i < BB * 64; i += 256) pairCnt[i] = 0;
    if (tid < BB * DD) pooled[tid] = 0.0f;
    if (tid == 0) *doneCnt = 0;
  }
  if (tid == 0) { sNon01 = 0; sNonpair = 0; sLow3 = 0; }
  __syncthreads();
  {
    const u32* aw = (const u32*)adj;
    int non01 = 0, nonpair = 0, low3 = 0;
    for (int i = tid; i < 4096; i += 256) {
      u32 x = aw[i];
      u32 lo = x & 0xFFFFu, hi = x >> 16;
      non01 |= (x > 1u);
      nonpair |= !((lo == 0u || lo == 0x3F80u) && (hi == 0u || hi == 0x3F80u));
      low3 |= (lo == 0x3F80u);
    }
    if (non01) atomicOr(&sNon01, 1);
    if (nonpair) atomicOr(&sNonpair, 1);
    if (low3) atomicOr(&sLow3, 1);
  }
  __syncthreads();
  // mode: 0=int32, 1=byte, 2=bf16, 3=f32
  int mode;
  if (!sNon01) mode = 0;
  else if (!sNonpair) mode = sLow3 ? 2 : 3;
  else mode = 1;

  int gid = blockIdx.x * 256 + tid;
  int w = gid & 15;
  long long row = gid >> 4;
  long long base = row * NN + (long long)w * 64;
  u64 bits = 0;
  if (mode == 3) {
    const uint4* p = (const uint4*)((const float*)adj + base);
    #pragma unroll
    for (int t = 0; t < 16; ++t) {
      uint4 x = p[t];
      if (x.x << 1) bits |= 1ull << (4 * t + 0);   // ignore -0.0
      if (x.y << 1) bits |= 1ull << (4 * t + 1);
      if (x.z << 1) bits |= 1ull << (4 * t + 2);
      if (x.w << 1) bits |= 1ull << (4 * t + 3);
    }
  } else if (mode == 0) {
    const uint4* p = (const uint4*)((const u32*)adj + base);
    #pragma unroll
    for (int t = 0; t < 16; ++t) {
      uint4 x = p[t];
      if (x.x) bits |= 1ull << (4 * t + 0);
      if (x.y) bits |= 1ull << (4 * t + 1);
      if (x.z) bits |= 1ull << (4 * t + 2);
      if (x.w) bits |= 1ull << (4 * t + 3);
    }
  } else if (mode == 2) {
    const uint4* p = (const uint4*)((const unsigned short*)adj + base);
    #pragma unroll
    for (int t = 0; t < 8; ++t) {
      uint4 x = p[t];
      u32 c[4] = {x.x, x.y, x.z, x.w};
      #pragma unroll
      for (int q = 0; q < 4; ++q) {
        if ((c[q] & 0x7FFFu)) bits |= 1ull << (8 * t + 2 * q + 0);
        if ((c[q] >> 16) & 0x7FFFu) bits |= 1ull << (8 * t + 2 * q + 1);
      }
    }
  } else {
    const uint4* p = (const uint4*)((const unsigned char*)adj + base);
    #pragma unroll
    for (int t = 0; t < 4; ++t) {
      uint4 x = p[t];
      u32 c[4] = {x.x, x.y, x.z, x.w};
      #pragma unroll
      for (int q = 0; q < 4; ++q)
        #pragma unroll
        for (int bb = 0; bb < 4; ++bb)
          if ((c[q] >> (8 * bb)) & 0xFFu) bits |= 1ull << (16 * t + 4 * q + bb);
    }
  }
  adjbits[gid] = bits;
}

// -------------------------------------------------------------- two-hop
// Standalone (r14 showed integrating it into k_attn costs +30us vs +8 here).
__global__ __launch_bounds__(256) void k_twohop(const u64* __restrict__ adjbits,
                                                u64* __restrict__ neighbits) {
  __shared__ unsigned short listL[4][NN];
  int wave = threadIdx.x >> 6, lane = threadIdx.x & 63;
  int row = blockIdx.x * 4 + wave;
  int b = row >> 10;
  int i = row & (NN - 1);
  int w = lane & 15;
  const u64* rowp = adjbits + (size_t)row * 16;
  u64 rw = rowp[w];
  unsigned short* list = listL[wave];
  int cnt = 0;
  #pragma unroll
  for (int sw = 0; sw < 16; ++sw) {
    u64 bits = __shfl(rw, sw, 64);
    int mybit = (int)((bits >> lane) & 1ull);
    int pre = __popcll(bits & ((1ull << lane) - 1ull));
    if (mybit) list[cnt + pre] = (unsigned short)(sw * 64 + lane);
    cnt += __popcll(bits);
  }
  __syncthreads();
  u64 acc = rw;
  if (w == (i >> 6)) acc |= 1ull << (i & 63);
  int g = lane >> 4;
  const u64* basep = adjbits + (size_t)b * NN * 16;
  for (int n = g; n < cnt; n += 4) {
    int j = list[n];
    acc |= basep[(size_t)j * 16 + w];
  }
  acc |= __shfl_xor(acc, 16, 64);
  acc |= __shfl_xor(acc, 32, 64);
  if (lane < 16) neighbits[(size_t)row * 16 + lane] = acc;
}

// ------------------------------------------------------------- attention
// r12 body frozen (proven ~36 us) + fused finalize WITHOUT device fences:
// rowAgg written via agent-scope atomic stores (per-access coherent, no
// flush); __threadfence_block (= pure s_waitcnt) orders them before the
// pair counter. Second block of each (b,chunk) pair merges its 16 rows ->
// atomicAdds pooled; last of 2048 blocks runs the MLP head (verified in r9).
// Lessons kept: no min-waves bound (r6/r7 spill), no it-loop unroll (r9),
// no all-thread __threadfence (r9), no cooperative launch (r13).
__global__ __launch_bounds__(256) void k_attn(
    const void* __restrict__ feats, const void* __restrict__ coors,
    const void* __restrict__ Wq,
    const void* __restrict__ wr1, const void* __restrict__ br1,
    const void* __restrict__ wr2, const void* __restrict__ br2,
    const float4* __restrict__ kvg, const float* __restrict__ czg,
    const int* __restrict__ gflags,
    const u64* __restrict__ neighbits, float* __restrict__ rowAgg,
    int* __restrict__ pairCnt, int* __restrict__ doneCnt,
    float* __restrict__ pooled,
    const void* __restrict__ w1v, const void* __restrict__ b1v,
    const void* __restrict__ w2v, const void* __restrict__ b2v,
    float* __restrict__ out) {
  __shared__ __align__(16) float4 kvL[512 * 3];  // 24 KB
  __shared__ float czL[512];                     // 2 KB
  __shared__ float wqL[25];
  __shared__ float qL[16 * DD], ciL[16 * 3];
  __shared__ float wrL[3][RH];
  __shared__ float sConst[2];  // [0]=C*log2e, [1]=br2*log2e (when fast)
  __shared__ int sFast, sOld, sDoneI;
  int bi = blockIdx.x;
  int b = bi >> 7, rem = bi & 127, chunk = rem >> 1, half = rem & 1;
  int j0 = half * 512;
  int tid = threadIdx.x;
  int wave = tid >> 6, lane = tid & 63;
  bool f32 = gflags[0] != 0;
  if (tid < 25) wqL[tid] = ldf(Wq, tid, f32);
  if (tid >= 64 && tid < 64 + RH) {
    int h = tid - 64;
    wrL[0][h] = ldf(wr1, h, f32);
    wrL[1][h] = ldf(br1, h, f32);
    wrL[2][h] = ldf(wr2, h, f32);
  }
  if (tid == 96) {
    float c = 0.0f;
    int ok = 1;
    #pragma unroll
    for (int h = 0; h < RH; ++h) {
      float w1h = ldf(wr1, h, f32);
      if (ldf(br1, h, f32) != 0.0f) ok = 0;
      if (w1h > 0.0f) c += w1h * ldf(wr2, h, f32);
    }
    sConst[0] = c * LOG2E;
    sConst[1] = ldf(br2, 0, f32) * LOG2E;
    sFast = ok;
  }
  // stage kv records + cz for this j-half: pure coalesced copy
  {
    const float4* src = kvg + ((size_t)(b * NN) + j0) * 3;
    for (int idx = tid; idx < 512 * 3; idx += 256) kvL[idx] = src[idx];
    const float* csrc = czg + (size_t)(b * NN) + j0;
    for (int idx = tid; idx < 512; idx += 256) czL[idx] = csrc[idx];
  }
  __syncthreads();
  int fast = sFast;
  // q (scaled by 1/sqrt(5), and log2e when fast) + ci for this chunk's rows
  if (tid < 16) {
    long long row = (long long)b * NN + chunk * 16 + tid;
    float f0 = ldf(feats, row * DD + 0, f32), f1 = ldf(feats, row * DD + 1, f32),
          f2 = ldf(feats, row * DD + 2, f32), f3 = ldf(feats, row * DD + 3, f32),
          f4 = ldf(feats, row * DD + 4, f32);
    float qsc = fast ? (0.4472135954999579f * LOG2E) : 0.4472135954999579f;
    #pragma unroll
    for (int e = 0; e < DD; ++e)
      qL[tid * DD + e] = (f0 * wqL[e] + f1 * wqL[5 + e] + f2 * wqL[10 + e] +
                          f3 * wqL[15 + e] + f4 * wqL[20 + e]) * qsc;
    #pragma unroll
    for (int c = 0; c < 3; ++c)
      ciL[tid * 3 + c] = ldf(coors, row * 3 + c, f32);
  }
  __syncthreads();

  int i0 = chunk * 16 + wave * 4;
  float q[4][DD], ci[4][3], l[4], A[4][DD];
  #pragma unroll
  for (int r = 0; r < 4; ++r) {
    #pragma unroll
    for (int e = 0; e < DD; ++e) q[r][e] = qL[(wave * 4 + r) * DD + e];
    #pragma unroll
    for (int c = 0; c < 3; ++c) ci[r][c] = ciL[(wave * 4 + r) * 3 + c];
    l[r] = 0.0f;
    #pragma unroll
    for (int e = 0; e < DD; ++e) A[r][e] = 0.0f;
  }
  const u64* nb = neighbits + ((size_t)(b * NN + i0)) * 16 + half * 8;
  float Cf = sConst[0], br2f = sConst[1];
  for (int it = 0; it < 8; ++it) {
    int j = it * 64 + lane;
    float4 ka = kvL[j * 3 + 0];
    float4 kb = kvL[j * 3 + 1];
    float4 kc = kvL[j * 3 + 2];
    float jx = kc.z, jy = kc.w, jz = czL[j];
    u64 nw[4];
    #pragma unroll
    for (int r = 0; r < 4; ++r) nw[r] = nb[(size_t)r * 16 + it];
    if (fast) {
      #pragma unroll
      for (int r = 0; r < 4; ++r) {
        float cx = jx - ci[r][0], cy = jy - ci[r][1], cz = jz - ci[r][2];
        float dist =
            __builtin_amdgcn_sqrtf(fmaf(cx, cx, fmaf(cy, cy, fmaf(cz, cz, 1e-8f))));
        float s = fmaf(q[r][0], ka.x, br2f);
        s = fmaf(q[r][1], ka.y, s);
        s = fmaf(q[r][2], ka.z, s);
        s = fmaf(q[r][3], ka.w, s);
        s = fmaf(q[r][4], kb.x, s);
        s = fmaf(Cf, dist, s);
        s = fminf(s, 126.0f);
        s = ((nw[r] >> lane) & 1ull) ? s : -150.0f;
        float p = __builtin_amdgcn_exp2f(s);
        l[r] += p;
        A[r][0] = fmaf(p, kb.y, A[r][0]);
        A[r][1] = fmaf(p, kb.z, A[r][1]);
        A[r][2] = fmaf(p, kb.w, A[r][2]);
        A[r][3] = fmaf(p, kc.x, A[r][3]);
        A[r][4] = fmaf(p, kc.y, A[r][4]);
      }
    } else {
      #pragma unroll
      for (int r = 0; r < 4; ++r) {
        float cx = jx - ci[r][0], cy = jy - ci[r][1], cz = jz - ci[r][2];
        float dist = sqrtf(fmaf(cx, cx, fmaf(cy, cy, fmaf(cz, cz, 1e-8f))));
        float rb = ldf(br2, 0, f32);
        #pragma unroll
        for (int h = 0; h < RH; ++h)
          rb += fmaxf(dist * wrL[0][h] + wrL[1][h], 0.0f) * wrL[2][h];
        float s = fmaf(q[r][0], ka.x, rb);
        s = fmaf(q[r][1], ka.y, s);
        s = fmaf(q[r][2], ka.z, s);
        s = fmaf(q[r][3], ka.w, s);
        s = fmaf(q[r][4], kb.x, s);
        s = fminf(s, 85.0f);
        s = ((nw[r] >> lane) & 1ull) ? s : -100.0f;
        float p = __expf(s);
        l[r] += p;
        A[r][0] = fmaf(p, kb.y, A[r][0]);
        A[r][1] = fmaf(p, kb.z, A[r][1]);
        A[r][2] = fmaf(p, kb.w, A[r][2]);
        A[r][3] = fmaf(p, kc.x, A[r][3]);
        A[r][4] = fmaf(p, kc.y, A[r][4]);
      }
    }
  }
  #pragma unroll
  for (int msk = 1; msk < 64; msk <<= 1) {
    #pragma unroll
    for (int r = 0; r < 4; ++r) {
      l[r] += __shfl_xor(l[r], msk, 64);
      A[r][0] += __shfl_xor(A[r][0], msk, 64);
      A[r][1] += __shfl_xor(A[r][1], msk, 64);
      A[r][2] += __shfl_xor(A[r][2], msk, 64);
      A[r][3] += __shfl_xor(A[r][3], msk, 64);
      A[r][4] += __shfl_xor(A[r][4], msk, 64);
    }
  }
  if (lane == 0) {
    #pragma unroll
    for (int r = 0; r < 4; ++r) {
      float* o = rowAgg + (((size_t)(b * NN + i0 + r)) * 2 + half) * 6;
      stG(o + 0, l[r]);
      stG(o + 1, A[r][0]); stG(o + 2, A[r][1]); stG(o + 3, A[r][2]);
      stG(o + 4, A[r][3]); stG(o + 5, A[r][4]);
    }
  }
  // ---- fused finalize: pair merge, then last-block MLP ----
  __threadfence_block();  // s_waitcnt only — stores (agent-coherent) complete
  __syncthreads();
  if (tid == 0) sOld = atomicAdd(&pairCnt[bi >> 1], 1);
  __syncthreads();
  if (sOld == 1) {
    float pe[DD] = {0.f, 0.f, 0.f, 0.f, 0.f};
    if (tid < 16) {
      size_t rid = (size_t)(b * NN + chunk * 16 + tid);
      const float* ra = rowAgg + rid * 12;
      float lsum = ldG(ra + 0) + ldG(ra + 6);
      float inv = (lsum > 0.f) ? 1.0f / lsum : 0.0f;
      long long fb = (long long)rid * DD;
      #pragma unroll
      for (int e = 0; e < DD; ++e)
        pe[e] = ldf(feats, fb + e, f32) + (ldG(ra + 1 + e) + ldG(ra + 7 + e)) * inv;
    }
    if (tid < 64) {
      #pragma unroll
      for (int off = 8; off >= 1; off >>= 1)
        #pragma unroll
        for (int e = 0; e < DD; ++e) pe[e] += __shfl_down(pe[e], off, 64);
    }
    if (tid == 0) {
      #pragma unroll
      for (int e = 0; e < DD; ++e) atomicAdd(&pooled[b * DD + e], pe[e]);
    }
  }
  __threadfence_block();
  __syncthreads();
  if (tid == 0) sDoneI = (atomicAdd(doneCnt, 1) == (int)gridDim.x - 1);
  __syncthreads();
  if (sDoneI) {
    int bb2 = tid >> 4, sub = tid & 15;
    float pl[DD];
    #pragma unroll
    for (int e = 0; e < DD; ++e)
      pl[e] = ldG(&pooled[bb2 * DD + e]) * (1.0f / 1024.0f);
    float a0 = 0.f, a1 = 0.f, a2 = 0.f;
    for (int jj = sub * 8; jj < sub * 8 + 8; ++jj) {
      float h = ldf(b1v, jj, f32);
      #pragma unroll
      for (int d = 0; d < DD; ++d)
        h = fmaf(pl[d], ldf(w1v, d * 128 + jj, f32), h);
      h = fmaxf(h, 0.0f);
      a0 = fmaf(h, ldf(w2v, jj * 3 + 0, f32), a0);
      a1 = fmaf(h, ldf(w2v, jj * 3 + 1, f32), a1);
      a2 = fmaf(h, ldf(w2v, jj * 3 + 2, f32), a2);
    }
    #pragma unroll
    for (int mk = 1; mk < 16; mk <<= 1) {
      a0 += __shfl_xor(a0, mk, 64);
      a1 += __shfl_xor(a1, mk, 64);
      a2 += __shfl_xor(a2, mk, 64);
    }
    if (sub == 0) {
      out[bb2 * 3 + 0] = a0 + ldf(b2v, 0, f32);
      out[bb2 * 3 + 1] = a1 + ldf(b2v, 1, f32);
      out[bb2 * 3 + 2] = a2 + ldf(b2v, 2, f32);
    }
  }
}

// ---------------------------------------------------------------- launch
extern "C" void kernel_launch(void* const* d_in, const int* in_sizes, int n_in,
                              void* d_out, int out_size, void* d_ws, size_t ws_size,
                              hipStream_t stream) {
  const void* adj = d_in[2];
  float* out = (float*)d_out;

  char* w = (char*)d_ws;
  int* gflags = (int*)w;                                   // 16 B
  float* pooled = (float*)(w + 64);                        // 80 f32
  int* doneCnt = (int*)(w + 448);                          // 1 int
  int* pairCnt = (int*)(w + 1024);                         // 1024 ints
  const size_t MB2 = (size_t)BB * NN * 16 * sizeof(u64);   // 2 MiB
  u64* adjbits = (u64*)(w + 8192);
  u64* neighbits = (u64*)(w + 8192 + MB2);
  float* rowAgg = (float*)(w + 8192 + 2 * MB2);            // 768 KiB
  float4* kvg = (float4*)(w + 8192 + 2 * MB2 + 786432);    // 768 KiB
  float* czg = (float*)(w + 8192 + 2 * MB2 + 2 * 786432);  // 64 KiB

  k_pack<<<PACK_BLOCKS + KV_BLOCKS, 256, 0, stream>>>(
      adj, d_in[0], d_in[1], d_in[4], d_in[5], d_in[6], adjbits, kvg, czg,
      gflags, pairCnt, doneCnt, pooled);
  k_twohop<<<BB * NN / 4, 256, 0, stream>>>(adjbits, neighbits);
  k_attn<<<BB * 128, 256, 0, stream>>>(d_in[0], d_in[1], d_in[3], d_in[7], d_in[8],
                                       d_in[9], d_in[10], kvg, czg, gflags,
                                       neighbits, rowAgg, pairCnt, doneCnt, pooled,
                                       d_in[11], d_in[12], d_in[13], d_in[14], out);
}

// Round 16
// 187.335 us; speedup vs baseline: 1.0885x; 1.0885x over previous
//
#include <hip/hip_runtime.h>
#include <hip/hip_bf16.h>

#define BB 16
#define NN 1024
#define DD 5
#define RH 8

typedef unsigned long long u64;
typedef unsigned int u32;
typedef __hip_bfloat16 bf16;

static __device__ __forceinline__ float tof(bf16 x) { return __bfloat162float(x); }
// runtime-dtype load: f32 storage if f==true else bf16
static __device__ __forceinline__ float ldf(const void* p, long long i, bool f) {
  return f ? ((const float*)p)[i] : tof(((const bf16*)p)[i]);
}

#define LOG2E 1.4426950408889634f
#define PACK_BLOCKS (BB * NN * 16 / 256)  // 1024
#define KV_BLOCKS (BB * NN / 256)         // 64

// Final state = the round-12 configuration (best measured: 188.1 us,
// absmax 0.0). Session lessons baked in as structure:
//  - 4 dispatches; kernel boundaries are the CHEAPEST cross-XCD sync on this
//    8-XCD part. Fusion attempts all lost: r9 all-thread __threadfence
//    (+160us, L2 serialization), r13 cooperative launch (fails to launch),
//    r14 twohop-in-attn (+30us redundant gathers), r15 agent-scope uncached
//    atomics (+48us, every store straight to HBM).
//  - no min-waves __launch_bounds__ arg (r6: spill 584 MB; r7: spill 51 MB);
//    let the allocator pick (VGPR 76, zero spill).
//  - no #pragma unroll on the it-loop (r9: 53->155us, giant-body stall).
//  - exp2 with log2e folded into q/C/br2 + raw sqrt (absmax-neutral).
//  - radial MLP collapsed to one fma when biases are zero (wave-uniform
//    fallback keeps generality).
//  - per-node k/v'/coords precomputed once (kvg/czg packed records); k_attn
//    staging is a pure coalesced float4 copy.
//  - adjacency dtype probed on-device (int32/byte/bf16/f32 storage).

// ---------------------------------------------------------------- pack + kv
__global__ __launch_bounds__(256) void k_pack(
    const void* __restrict__ adj, const void* __restrict__ feats,
    const void* __restrict__ coors,
    const void* __restrict__ Wk, const void* __restrict__ Wv,
    const void* __restrict__ Wo,
    u64* __restrict__ adjbits, float4* __restrict__ kvg,
    float* __restrict__ czg, int* __restrict__ gflags) {
  __shared__ int sNon01, sNonpair, sLow3;
  __shared__ int sCnt[4];
  __shared__ float wkL[25], wvL[25], woL[25];
  int tid = threadIdx.x;

  if (blockIdx.x >= PACK_BLOCKS) {
    // ---------------- kv precompute role ----------------
    int kb = blockIdx.x - PACK_BLOCKS;
    {
      u32 x = ((const u32*)feats)[tid];
      u32 lo = x & 0xFFFFu;
      int e = (int)((lo >> 7) & 0xFFu);
      bool insane = !(lo == 0u || (e >= 90 && e <= 150));
      u64 m = __ballot(insane);
      if ((tid & 63) == 0) sCnt[tid >> 6] = (int)__popcll(m);
    }
    __syncthreads();
    bool f32 = (sCnt[0] + sCnt[1] + sCnt[2] + sCnt[3]) > 64;
    if (tid < 25) {
      wkL[tid] = ldf(Wk, tid, f32);
      wvL[tid] = ldf(Wv, tid, f32);
      woL[tid] = ldf(Wo, tid, f32);
    }
    if (kb == 0 && tid == 0) gflags[0] = f32 ? 1 : 0;
    __syncthreads();
    long long node = (long long)kb * 256 + tid;  // < BB*NN
    float f0 = ldf(feats, node * DD + 0, f32), f1 = ldf(feats, node * DD + 1, f32),
          f2 = ldf(feats, node * DD + 2, f32), f3 = ldf(feats, node * DD + 3, f32),
          f4 = ldf(feats, node * DD + 4, f32);
    float k[DD], tv[DD], v[DD];
    #pragma unroll
    for (int e = 0; e < DD; ++e) {
      k[e] = f0 * wkL[e] + f1 * wkL[5 + e] + f2 * wkL[10 + e] + f3 * wkL[15 + e] +
             f4 * wkL[20 + e];
      tv[e] = f0 * wvL[e] + f1 * wvL[5 + e] + f2 * wvL[10 + e] + f3 * wvL[15 + e] +
              f4 * wvL[20 + e];
    }
    #pragma unroll
    for (int e = 0; e < DD; ++e)
      v[e] = tv[0] * woL[e] + tv[1] * woL[5 + e] + tv[2] * woL[10 + e] +
             tv[3] * woL[15 + e] + tv[4] * woL[20 + e];
    float cx = ldf(coors, node * 3 + 0, f32);
    float cy = ldf(coors, node * 3 + 1, f32);
    float cz = ldf(coors, node * 3 + 2, f32);
    kvg[node * 3 + 0] = make_float4(k[0], k[1], k[2], k[3]);
    kvg[node * 3 + 1] = make_float4(k[4], v[0], v[1], v[2]);
    kvg[node * 3 + 2] = make_float4(v[3], v[4], cx, cy);
    czg[node] = cz;
    return;
  }

  // ---------------- adjacency pack role ----------------
  if (tid == 0) { sNon01 = 0; sNonpair = 0; sLow3 = 0; }
  __syncthreads();
  {
    const u32* aw = (const u32*)adj;
    int non01 = 0, nonpair = 0, low3 = 0;
    for (int i = tid; i < 4096; i += 256) {
      u32 x = aw[i];
      u32 lo = x & 0xFFFFu, hi = x >> 16;
      non01 |= (x > 1u);
      nonpair |= !((lo == 0u || lo == 0x3F80u) && (hi == 0u || hi == 0x3F80u));
      low3 |= (lo == 0x3F80u);
    }
    if (non01) atomicOr(&sNon01, 1);
    if (nonpair) atomicOr(&sNonpair, 1);
    if (low3) atomicOr(&sLow3, 1);
  }
  __syncthreads();
  // mode: 0=int32, 1=byte, 2=bf16, 3=f32
  int mode;
  if (!sNon01) mode = 0;
  else if (!sNonpair) mode = sLow3 ? 2 : 3;
  else mode = 1;

  int gid = blockIdx.x * 256 + tid;
  int w = gid & 15;
  long long row = gid >> 4;
  long long base = row * NN + (long long)w * 64;
  u64 bits = 0;
  if (mode == 3) {
    const uint4* p = (const uint4*)((const float*)adj + base);
    #pragma unroll
    for (int t = 0; t < 16; ++t) {
      uint4 x = p[t];
      if (x.x << 1) bits |= 1ull << (4 * t + 0);   // ignore -0.0
      if (x.y << 1) bits |= 1ull << (4 * t + 1);
      if (x.z << 1) bits |= 1ull << (4 * t + 2);
      if (x.w << 1) bits |= 1ull << (4 * t + 3);
    }
  } else if (mode == 0) {
    const uint4* p = (const uint4*)((const u32*)adj + base);
    #pragma unroll
    for (int t = 0; t < 16; ++t) {
      uint4 x = p[t];
      if (x.x) bits |= 1ull << (4 * t + 0);
      if (x.y) bits |= 1ull << (4 * t + 1);
      if (x.z) bits |= 1ull << (4 * t + 2);
      if (x.w) bits |= 1ull << (4 * t + 3);
    }
  } else if (mode == 2) {
    const uint4* p = (const uint4*)((const unsigned short*)adj + base);
    #pragma unroll
    for (int t = 0; t < 8; ++t) {
      uint4 x = p[t];
      u32 c[4] = {x.x, x.y, x.z, x.w};
      #pragma unroll
      for (int q = 0; q < 4; ++q) {
        if ((c[q] & 0x7FFFu)) bits |= 1ull << (8 * t + 2 * q + 0);
        if ((c[q] >> 16) & 0x7FFFu) bits |= 1ull << (8 * t + 2 * q + 1);
      }
    }
  } else {
    const uint4* p = (const uint4*)((const unsigned char*)adj + base);
    #pragma unroll
    for (int t = 0; t < 4; ++t) {
      uint4 x = p[t];
      u32 c[4] = {x.x, x.y, x.z, x.w};
      #pragma unroll
      for (int q = 0; q < 4; ++q)
        #pragma unroll
        for (int bb = 0; bb < 4; ++bb)
          if ((c[q] >> (8 * bb)) & 0xFFu) bits |= 1ull << (16 * t + 4 * q + bb);
    }
  }
  adjbits[gid] = bits;
}

// -------------------------------------------------------------- two-hop
__global__ __launch_bounds__(256) void k_twohop(const u64* __restrict__ adjbits,
                                                u64* __restrict__ neighbits) {
  __shared__ unsigned short listL[4][NN];
  int wave = threadIdx.x >> 6, lane = threadIdx.x & 63;
  int row = blockIdx.x * 4 + wave;
  int b = row >> 10;
  int i = row & (NN - 1);
  int w = lane & 15;
  const u64* rowp = adjbits + (size_t)row * 16;
  u64 rw = rowp[w];
  unsigned short* list = listL[wave];
  int cnt = 0;
  #pragma unroll
  for (int sw = 0; sw < 16; ++sw) {
    u64 bits = __shfl(rw, sw, 64);
    int mybit = (int)((bits >> lane) & 1ull);
    int pre = __popcll(bits & ((1ull << lane) - 1ull));
    if (mybit) list[cnt + pre] = (unsigned short)(sw * 64 + lane);
    cnt += __popcll(bits);
  }
  __syncthreads();
  u64 acc = rw;
  if (w == (i >> 6)) acc |= 1ull << (i & 63);
  int g = lane >> 4;
  const u64* basep = adjbits + (size_t)b * NN * 16;
  for (int n = g; n < cnt; n += 4) {
    int j = list[n];
    acc |= basep[(size_t)j * 16 + w];
  }
  acc |= __shfl_xor(acc, 16, 64);
  acc |= __shfl_xor(acc, 32, 64);
  if (lane < 16) neighbits[(size_t)row * 16 + lane] = acc;
}

// ------------------------------------------------------------- attention
__global__ __launch_bounds__(256) void k_attn(
    const void* __restrict__ feats, const void* __restrict__ coors,
    const void* __restrict__ Wq,
    const void* __restrict__ wr1, const void* __restrict__ br1,
    const void* __restrict__ wr2, const void* __restrict__ br2,
    const float4* __restrict__ kvg, const float* __restrict__ czg,
    const int* __restrict__ gflags,
    const u64* __restrict__ neighbits, float* __restrict__ rowAgg) {
  __shared__ __align__(16) float4 kvL[512 * 3];  // 24 KB
  __shared__ float czL[512];                     // 2 KB
  __shared__ float wqL[25];
  __shared__ float qL[16 * DD], ciL[16 * 3];
  __shared__ float wrL[3][RH];
  __shared__ float sConst[2];  // [0]=C*log2e, [1]=br2*log2e (when fast)
  __shared__ int sFast;
  int bi = blockIdx.x;
  int b = bi >> 7, rem = bi & 127, chunk = rem >> 1, half = rem & 1;
  int j0 = half * 512;
  int tid = threadIdx.x;
  bool f32 = gflags[0] != 0;
  if (tid < 25) wqL[tid] = ldf(Wq, tid, f32);
  if (tid >= 64 && tid < 64 + RH) {
    int h = tid - 64;
    wrL[0][h] = ldf(wr1, h, f32);
    wrL[1][h] = ldf(br1, h, f32);
    wrL[2][h] = ldf(wr2, h, f32);
  }
  if (tid == 96) {
    float c = 0.0f;
    int ok = 1;
    #pragma unroll
    for (int h = 0; h < RH; ++h) {
      float w1h = ldf(wr1, h, f32);
      if (ldf(br1, h, f32) != 0.0f) ok = 0;
      if (w1h > 0.0f) c += w1h * ldf(wr2, h, f32);
    }
    sConst[0] = c * LOG2E;
    sConst[1] = ldf(br2, 0, f32) * LOG2E;
    sFast = ok;
  }
  // stage kv records + cz for this j-half: pure coalesced copy
  {
    const float4* src = kvg + ((size_t)(b * NN) + j0) * 3;
    for (int idx = tid; idx < 512 * 3; idx += 256) kvL[idx] = src[idx];
    const float* csrc = czg + (size_t)(b * NN) + j0;
    for (int idx = tid; idx < 512; idx += 256) czL[idx] = csrc[idx];
  }
  __syncthreads();
  int fast = sFast;
  // q (scaled by 1/sqrt(5), and log2e when fast) + ci for this chunk's rows
  if (tid < 16) {
    long long row = (long long)b * NN + chunk * 16 + tid;
    float f0 = ldf(feats, row * DD + 0, f32), f1 = ldf(feats, row * DD + 1, f32),
          f2 = ldf(feats, row * DD + 2, f32), f3 = ldf(feats, row * DD + 3, f32),
          f4 = ldf(feats, row * DD + 4, f32);
    float qsc = fast ? (0.4472135954999579f * LOG2E) : 0.4472135954999579f;
    #pragma unroll
    for (int e = 0; e < DD; ++e)
      qL[tid * DD + e] = (f0 * wqL[e] + f1 * wqL[5 + e] + f2 * wqL[10 + e] +
                          f3 * wqL[15 + e] + f4 * wqL[20 + e]) * qsc;
    #pragma unroll
    for (int c = 0; c < 3; ++c)
      ciL[tid * 3 + c] = ldf(coors, row * 3 + c, f32);
  }
  __syncthreads();

  int g = tid >> 6, lane = tid & 63;
  int i0 = chunk * 16 + g * 4;
  float q[4][DD], ci[4][3], l[4], A[4][DD];
  #pragma unroll
  for (int r = 0; r < 4; ++r) {
    #pragma unroll
    for (int e = 0; e < DD; ++e) q[r][e] = qL[(g * 4 + r) * DD + e];
    #pragma unroll
    for (int c = 0; c < 3; ++c) ci[r][c] = ciL[(g * 4 + r) * 3 + c];
    l[r] = 0.0f;
    #pragma unroll
    for (int e = 0; e < DD; ++e) A[r][e] = 0.0f;
  }
  const u64* nb = neighbits + ((size_t)(b * NN + i0)) * 16 + half * 8;
  float Cf = sConst[0], br2f = sConst[1];
  for (int it = 0; it < 8; ++it) {
    int j = it * 64 + lane;
    float4 ka = kvL[j * 3 + 0];
    float4 kb = kvL[j * 3 + 1];
    float4 kc = kvL[j * 3 + 2];
    float jx = kc.z, jy = kc.w, jz = czL[j];
    u64 nw[4];
    #pragma unroll
    for (int r = 0; r < 4; ++r) nw[r] = nb[(size_t)r * 16 + it];
    if (fast) {
      #pragma unroll
      for (int r = 0; r < 4; ++r) {
        float cx = jx - ci[r][0], cy = jy - ci[r][1], cz = jz - ci[r][2];
        float dist =
            __builtin_amdgcn_sqrtf(fmaf(cx, cx, fmaf(cy, cy, fmaf(cz, cz, 1e-8f))));
        float s = fmaf(q[r][0], ka.x, br2f);
        s = fmaf(q[r][1], ka.y, s);
        s = fmaf(q[r][2], ka.z, s);
        s = fmaf(q[r][3], ka.w, s);
        s = fmaf(q[r][4], kb.x, s);
        s = fmaf(Cf, dist, s);
        s = fminf(s, 126.0f);
        s = ((nw[r] >> lane) & 1ull) ? s : -150.0f;
        float p = __builtin_amdgcn_exp2f(s);
        l[r] += p;
        A[r][0] = fmaf(p, kb.y, A[r][0]);
        A[r][1] = fmaf(p, kb.z, A[r][1]);
        A[r][2] = fmaf(p, kb.w, A[r][2]);
        A[r][3] = fmaf(p, kc.x, A[r][3]);
        A[r][4] = fmaf(p, kc.y, A[r][4]);
      }
    } else {
      #pragma unroll
      for (int r = 0; r < 4; ++r) {
        float cx = jx - ci[r][0], cy = jy - ci[r][1], cz = jz - ci[r][2];
        float dist = sqrtf(fmaf(cx, cx, fmaf(cy, cy, fmaf(cz, cz, 1e-8f))));
        float rb = ldf(br2, 0, f32);
        #pragma unroll
        for (int h = 0; h < RH; ++h)
          rb += fmaxf(dist * wrL[0][h] + wrL[1][h], 0.0f) * wrL[2][h];
        float s = fmaf(q[r][0], ka.x, rb);
        s = fmaf(q[r][1], ka.y, s);
        s = fmaf(q[r][2], ka.z, s);
        s = fmaf(q[r][3], ka.w, s);
        s = fmaf(q[r][4], kb.x, s);
        s = fminf(s, 85.0f);
        s = ((nw[r] >> lane) & 1ull) ? s : -100.0f;
        float p = __expf(s);
        l[r] += p;
        A[r][0] = fmaf(p, kb.y, A[r][0]);
        A[r][1] = fmaf(p, kb.z, A[r][1]);
        A[r][2] = fmaf(p, kb.w, A[r][2]);
        A[r][3] = fmaf(p, kc.x, A[r][3]);
        A[r][4] = fmaf(p, kc.y, A[r][4]);
      }
    }
  }
  #pragma unroll
  for (int msk = 1; msk < 64; msk <<= 1) {
    #pragma unroll
    for (int r = 0; r < 4; ++r) {
      l[r] += __shfl_xor(l[r], msk, 64);
      A[r][0] += __shfl_xor(A[r][0], msk, 64);
      A[r][1] += __shfl_xor(A[r][1], msk, 64);
      A[r][2] += __shfl_xor(A[r][2], msk, 64);
      A[r][3] += __shfl_xor(A[r][3], msk, 64);
      A[r][4] += __shfl_xor(A[r][4], msk, 64);
    }
  }
  if (lane == 0) {
    #pragma unroll
    for (int r = 0; r < 4; ++r) {
      float* o = rowAgg + (((size_t)(b * NN + i0 + r)) * 2 + half) * 6;
      o[0] = l[r];
      o[1] = A[r][0]; o[2] = A[r][1]; o[3] = A[r][2]; o[4] = A[r][3]; o[5] = A[r][4];
    }
  }
}

// --------------------------------------------------- finalize: pool + MLP
__global__ __launch_bounds__(256) void k_final(
    const void* __restrict__ feats, const float* __restrict__ rowAgg,
    const int* __restrict__ gflags,
    const void* __restrict__ w1, const void* __restrict__ b1,
    const void* __restrict__ w2, const void* __restrict__ b2,
    float* __restrict__ out) {
  __shared__ float waveL[4][DD];
  __shared__ float poolL[DD];
  __shared__ float hL[128];
  int b = blockIdx.x, tid = threadIdx.x;
  bool f32 = gflags[0] != 0;
  float pe[DD] = {0.f, 0.f, 0.f, 0.f, 0.f};
  for (int n = tid; n < NN; n += 256) {
    const float* ag = rowAgg + ((size_t)(b * NN + n)) * 12;
    float l = ag[0] + ag[6];
    float inv = (l > 0.f) ? 1.0f / l : 0.0f;
    long long base = ((long long)b * NN + n) * DD;
    #pragma unroll
    for (int e = 0; e < DD; ++e)
      pe[e] += ldf(feats, base + e, f32) + (ag[1 + e] + ag[7 + e]) * inv;
  }
  #pragma unroll
  for (int off = 32; off >= 1; off >>= 1)
    #pragma unroll
    for (int e = 0; e < DD; ++e) pe[e] += __shfl_down(pe[e], off, 64);
  int wave = tid >> 6, lane = tid & 63;
  if (lane == 0)
    #pragma unroll
    for (int e = 0; e < DD; ++e) waveL[wave][e] = pe[e];
  __syncthreads();
  if (tid < DD)
    poolL[tid] = (waveL[0][tid] + waveL[1][tid] + waveL[2][tid] + waveL[3][tid]) *
                 (1.0f / 1024.0f);
  __syncthreads();
  if (tid < 128) {
    float acc = ldf(b1, tid, f32);
    #pragma unroll
    for (int d = 0; d < DD; ++d)
      acc = fmaf(poolL[d], ldf(w1, d * 128 + tid, f32), acc);
    hL[tid] = fmaxf(acc, 0.0f);
  }
  __syncthreads();
  if (tid < 3) {
    float s = ldf(b2, tid, f32);
    for (int j = 0; j < 128; ++j) s = fmaf(hL[j], ldf(w2, j * 3 + tid, f32), s);
    out[b * 3 + tid] = s;
  }
}

// ---------------------------------------------------------------- launch
extern "C" void kernel_launch(void* const* d_in, const int* in_sizes, int n_in,
                              void* d_out, int out_size, void* d_ws, size_t ws_size,
                              hipStream_t stream) {
  const void* adj = d_in[2];
  float* out = (float*)d_out;

  char* w = (char*)d_ws;
  int* gflags = (int*)w;                                   // 16 B
  const size_t MB2 = (size_t)BB * NN * 16 * sizeof(u64);   // 2 MiB
  u64* adjbits = (u64*)(w + 512);
  u64* neighbits = (u64*)(w + 512 + MB2);
  float* rowAgg = (float*)(w + 512 + 2 * MB2);             // 768 KiB
  float4* kvg = (float4*)(w + 512 + 2 * MB2 + 786432);     // 768 KiB
  float* czg = (float*)(w + 512 + 2 * MB2 + 2 * 786432);   // 64 KiB

  k_pack<<<PACK_BLOCKS + KV_BLOCKS, 256, 0, stream>>>(
      adj, d_in[0], d_in[1], d_in[4], d_in[5], d_in[6], adjbits, kvg, czg, gflags);
  k_twohop<<<BB * NN / 4, 256, 0, stream>>>(adjbits, neighbits);
  k_attn<<<BB * 128, 256, 0, stream>>>(d_in[0], d_in[1], d_in[3], d_in[7], d_in[8],
                                       d_in[9], d_in[10], kvg, czg, gflags,
                                       neighbits, rowAgg);
  k_final<<<BB, 256, 0, stream>>>(d_in[0], rowAgg, gflags, d_in[11], d_in[12],
                                  d_in[13], d_in[14], out);
}